// Round 14
// baseline (304.606 us; speedup 1.0000x reference)
//
#include <hip/hip_runtime.h>

#define NBATCH 8
#define NN     207
#define DHID   256
#define LL     2484      // 12*207
#define LLP    2496      // padded to multiple of 32
#define RT     12        // query rows per block (208 blocks/batch: 208*12=2496)
#define NBLK   208
#define GCOL   2560      // G-tile padded cols (swizzle headroom)
#define TILES  78        // LLP/32
#define TPW    10        // j-tiles per wave (8 waves x 10 >= 78)
#define SENT   0xFFFFu
#define LNEPS  1e-5f

typedef __attribute__((ext_vector_type(8)))  short bf16x8;
typedef __attribute__((ext_vector_type(8)))  unsigned short u16x8;
typedef __attribute__((ext_vector_type(16))) float f32x16;

__device__ __forceinline__ short f2bf(float f) {
    unsigned u = __float_as_uint(f);
    unsigned r = (u + 0x7FFFu + ((u >> 16) & 1u)) >> 16;
    return (short)r;
}

// ---------------- Kernel 1: LayerNorm + Q/K projections ----------------
__global__ __launch_bounds__(256) void k_lnproj(
    const float* __restrict__ x, const float* __restrict__ Wq, const float* __restrict__ bq,
    const float* __restrict__ Wk, const float* __restrict__ bk,
    const float* __restrict__ gamma, const float* __restrict__ beta,
    float* __restrict__ Xn, float* __restrict__ Qb, short* __restrict__ Kbf)
{
    __shared__ float xrow[4][64];
    int w = threadIdx.x >> 6, lane = threadIdx.x & 63;
    size_t row = (size_t)blockIdx.x * 4 + w;
    float xv = x[row * 64 + lane];
    float m = xv;
    #pragma unroll
    for (int o = 32; o; o >>= 1) m += __shfl_xor(m, o, 64);
    m *= (1.0f / 64.0f);
    float dv = xv - m;
    float var = dv * dv;
    #pragma unroll
    for (int o = 32; o; o >>= 1) var += __shfl_xor(var, o, 64);
    var *= (1.0f / 64.0f);
    float xg = dv * (1.0f / sqrtf(var + LNEPS)) * gamma[lane] + beta[lane];
    Xn[row * 64 + lane] = xg;
    xrow[w][lane] = xg;
    __syncthreads();
    float q = bq[lane], k = bk[lane];
    #pragma unroll 8
    for (int e = 0; e < 64; e++) {
        float xe = xrow[w][e];
        q += xe * Wq[e * 64 + lane];
        k += xe * Wk[e * 64 + lane];
    }
    int br = (int)(row / LL);
    int jl = (int)(row - (size_t)br * LL);
    Qb[((size_t)br * LLP + jl) * 64 + lane] = q;
    Kbf[((size_t)br * LLP + jl) * 64 + lane] = f2bf(k);
}

// ---------------- Kernel 1b: transpose Xn -> bf16 X^T, zero all pads ----------------
__global__ __launch_bounds__(256) void k_prep(
    const float* __restrict__ Xn, short* __restrict__ XbfT,
    short* __restrict__ Kbf, float* __restrict__ Qb)
{
    __shared__ float tile[64][65];
    int bb = blockIdx.x & 7;
    int jt = blockIdx.x >> 3;          // 0..38
    int j0 = jt * 64;
    for (int i = threadIdx.x; i < 4096; i += 256) {
        int jl = i >> 6, d = i & 63;
        int j = j0 + jl;
        tile[jl][d] = (j < LL) ? Xn[((size_t)bb * LL + j) * 64 + d] : 0.f;
    }
    __syncthreads();
    for (int i = threadIdx.x; i < 4096; i += 256) {
        int d = i >> 6, jl = i & 63;
        XbfT[((size_t)bb * 64 + d) * LLP + j0 + jl] = f2bf(tile[jl][d]);
    }
    if (jt == 38) {
        for (int i = threadIdx.x; i < (LLP - LL) * 64; i += 256) {
            int jl = i >> 6, d = i & 63;
            Kbf[((size_t)bb * LLP + LL + jl) * 64 + d] = 0;
            Qb [((size_t)bb * LLP + LL + jl) * 64 + d] = 0.f;
        }
    }
}

// ---------------- Kernel 2: fused attn, 512 thr, G in LDS (2 blocks/CU), pipelined ----------------
__global__ __launch_bounds__(512, 4) void k_attn(
    const float* __restrict__ Xn, const float* __restrict__ Qb,
    const short* __restrict__ Kbf, const short* __restrict__ XbfT,
    const float* __restrict__ stg, const int* __restrict__ topk_p,
    float* __restrict__ Z)
{
    __shared__ __align__(16) unsigned short Gt[RT * GCOL];   // 61,440 B
    __shared__ __align__(16) unsigned hist[RT * 256];        // 12,288 B (512-bin packed u16x2)
    __shared__ int gmax_lds[RT];
    __shared__ unsigned thr_lds[RT];
    float* redf = (float*)hist;            // union: red[RT*65] + rowsum[RT], hist dead after scan
    float* rowsum = redf + RT * 65;

    int tid = threadIdx.x;
    int lane = tid & 63, wv = tid >> 6;    // wv in [0,8)
    int hi = lane >> 5, l31 = lane & 31;
    int b = blockIdx.x & 7;
    int tile = blockIdx.x >> 3;            // 0..207
    int row0 = tile * RT;

    // ---- init: Gt = sentinel, hist = 0, gmax = 0 ----
    for (int i = tid; i < RT * GCOL / 2; i += 512) ((unsigned*)Gt)[i] = 0xFFFFFFFFu;
    for (int i = tid; i < RT * 256; i += 512) hist[i] = 0u;
    if (tid < RT) gmax_lds[tid] = 0;

    int keff;
    { int tk = *topk_p; keff = (tk < 5) ? tk * NN : tk; }

    // Q A-fragments: row = row0 + l31 (rows >= RT give garbage -> discarded downstream)
    bf16x8 qf[4];
    {
        const float* qp = Qb + ((size_t)b * LLP + row0 + l31) * 64 + hi * 8;
        #pragma unroll
        for (int kk = 0; kk < 4; kk++) {
            bf16x8 f;
            #pragma unroll
            for (int e = 0; e < 8; e++) f[e] = f2bf(qp[kk * 16 + e]);
            qf[kk] = f;
        }
    }
    const float* stgb = stg + (size_t)b * LL * LL;
    int kt0 = wv * TPW;
    int kt1 = (kt0 + TPW < TILES) ? kt0 + TPW : TILES;
    __syncthreads();   // init visible

    // ---- Phase A (double-buffered): coalesced stg + MFMA -> u16 g in LDS + hist + gmax ----
    int gmx[16];
    #pragma unroll
    for (int i = 0; i < 16; i++) gmx[i] = 0;

    float svsA[16]; bf16x8 kvA[4];
    if (kt0 < kt1) {
        int j = kt0 * 32 + l31;
        #pragma unroll
        for (int reg = 0; reg < 16; reg++) {
            int trow = (reg & 3) + 8 * (reg >> 2) + 4 * hi;
            int grow = row0 + trow;
            bool v = (j < LL) && (trow < RT) && (grow < LL);
            svsA[reg] = v ? stgb[(size_t)grow * LL + j] : 0.f;
        }
        const short* kbase = Kbf + ((size_t)b * LLP + j) * 64 + hi * 8;
        kvA[0] = *(const bf16x8*)(kbase);
        kvA[1] = *(const bf16x8*)(kbase + 16);
        kvA[2] = *(const bf16x8*)(kbase + 32);
        kvA[3] = *(const bf16x8*)(kbase + 48);
    }
    for (int kt = kt0; kt < kt1; ++kt) {
        float svsB[16]; bf16x8 kvB[4];
        if (kt + 1 < kt1) {
            int jn = (kt + 1) * 32 + l31;
            #pragma unroll
            for (int reg = 0; reg < 16; reg++) {
                int trow = (reg & 3) + 8 * (reg >> 2) + 4 * hi;
                int grow = row0 + trow;
                bool v = (jn < LL) && (trow < RT) && (grow < LL);
                svsB[reg] = v ? stgb[(size_t)grow * LL + jn] : 0.f;
            }
            const short* kbase = Kbf + ((size_t)b * LLP + jn) * 64 + hi * 8;
            kvB[0] = *(const bf16x8*)(kbase);
            kvB[1] = *(const bf16x8*)(kbase + 16);
            kvB[2] = *(const bf16x8*)(kbase + 32);
            kvB[3] = *(const bf16x8*)(kbase + 48);
        }
        int j = kt * 32 + l31;
        bool vj = (j < LL);
        f32x16 c = {0.f,0.f,0.f,0.f,0.f,0.f,0.f,0.f,0.f,0.f,0.f,0.f,0.f,0.f,0.f,0.f};
        c = __builtin_amdgcn_mfma_f32_32x32x16_bf16(qf[0], kvA[0], c, 0, 0, 0);
        c = __builtin_amdgcn_mfma_f32_32x32x16_bf16(qf[1], kvA[1], c, 0, 0, 0);
        c = __builtin_amdgcn_mfma_f32_32x32x16_bf16(qf[2], kvA[2], c, 0, 0, 0);
        c = __builtin_amdgcn_mfma_f32_32x32x16_bf16(qf[3], kvA[3], c, 0, 0, 0);
        #pragma unroll
        for (int reg = 0; reg < 16; reg++) {
            int trow = (reg & 3) + 8 * (reg >> 2) + 4 * hi;
            int grow = row0 + trow;
            bool v = vj && (trow < RT) && (grow < LL);
            float sg = 1.0f / (1.0f + __expf(c[reg] * -0.125f));
            float s = sg * svsA[reg];
            int g = (int)(s * 65536.0f); g = (g > 65534) ? 65534 : g;
            if (v) {
                unsigned col = (unsigned)j ^ ((unsigned)(trow & 15) << 3);
                Gt[trow * GCOL + col] = (unsigned short)g;
                atomicAdd(&hist[trow * 256 + (g >> 8)], 1u << (((g >> 7) & 1) << 4));
                gmx[reg] = (g > gmx[reg]) ? g : gmx[reg];
            }
        }
        #pragma unroll
        for (int i = 0; i < 16; i++) svsA[i] = svsB[i];
        #pragma unroll
        for (int i = 0; i < 4; i++) kvA[i] = kvB[i];
    }
    #pragma unroll
    for (int reg = 0; reg < 16; reg++) {
        int v = gmx[reg];
        #pragma unroll
        for (int off = 1; off < 32; off <<= 1) {
            int o2 = __shfl_xor(v, off, 64);
            v = (o2 > v) ? o2 : v;
        }
        if (l31 == 0) {
            int trow = (reg & 3) + 8 * (reg >> 2) + 4 * hi;
            if (trow < RT) atomicMax(&gmax_lds[trow], v);
        }
    }
    __syncthreads();   // Gt + hist + gmax complete

    // ---- Phase B: 512-bin scan per row -> threshold (keep g >= thrge) ----
    #pragma unroll 1
    for (int row = wv; row < RT; row += 8) {
        const unsigned* h = &hist[row * 256];
        unsigned w0 = h[lane * 4 + 0], w1 = h[lane * 4 + 1];
        unsigned w2 = h[lane * 4 + 2], w3 = h[lane * 4 + 3];
        unsigned cb[8] = {w0 & 0xFFFFu, w0 >> 16, w1 & 0xFFFFu, w1 >> 16,
                          w2 & 0xFFFFu, w2 >> 16, w3 & 0xFFFFu, w3 >> 16};
        unsigned S = cb[0] + cb[1] + cb[2] + cb[3] + cb[4] + cb[5] + cb[6] + cb[7];
        unsigned T = S;
        #pragma unroll
        for (int off = 1; off < 64; off <<= 1) {
            unsigned t = __shfl_down(T, off, 64);
            T += (lane + off < 64) ? t : 0u;
        }
        unsigned Tn = T - S;
        unsigned sfx[9];
        sfx[8] = Tn;
        #pragma unroll
        for (int i = 7; i >= 0; i--) sfx[i] = cb[i] + sfx[i + 1];
        unsigned kr = (unsigned)keff;
        int hit = -1; unsigned nk = 0, mm = 0;
        #pragma unroll
        for (int i = 0; i < 8; i++) {
            if (sfx[i] >= kr && sfx[i + 1] < kr) { hit = i; nk = kr - sfx[i + 1]; mm = cb[i]; }
        }
        unsigned long long mask = __ballot(hit >= 0);
        if (mask == 0ull) {
            if (lane == 0) thr_lds[row] = 65535u;
        } else {
            int src = __ffsll(mask) - 1;
            int bini = __shfl(hit, src, 64);
            nk = (unsigned)__shfl((int)nk, src, 64);
            mm = (unsigned)__shfl((int)mm, src, 64);
            if (lane == 0) {
                int bin = src * 8 + bini;
                int drop = (2u * nk <= mm) ? 1 : 0;
                int thrge = bin * 128 + (drop ? 128 : 0);
                if (thrge > 65535) thrge = 65535;
                thr_lds[row] = (unsigned)thrge;
            }
        }
    }
    __syncthreads();   // scans done reading hist

    // ---- re-purpose hist region as PV accumulators ----
    for (int i = tid; i < RT * 65 + RT; i += 512) redf[i] = 0.f;
    __syncthreads();

    // ---- Phase C (double-buffered): PV from LDS G-tile ----
    bool av = (l31 < RT);
    int arow = av ? l31 : 0;               // clamp pointer; invalid lanes output 0
    int agmax = av ? gmax_lds[arow] : -1;
    unsigned athr = av ? thr_lds[arow] : 65535u;
    unsigned swz = ((unsigned)(arow & 15)) << 3;
    const unsigned short* gp = &Gt[arow * GCOL];
    const short* xb0 = XbfT + ((size_t)b * 64 + l31) * LLP + hi * 8;
    const short* xb1 = XbfT + ((size_t)b * 64 + 32 + l31) * LLP + hi * 8;
    f32x16 p0 = {0.f,0.f,0.f,0.f,0.f,0.f,0.f,0.f,0.f,0.f,0.f,0.f,0.f,0.f,0.f,0.f};
    f32x16 p1 = p0;
    float smr = 0.f;

    bf16x8 xA[4];
    if (kt0 < kt1) {
        int j0 = kt0 * 32;
        xA[0] = *(const bf16x8*)(xb0 + j0);
        xA[1] = *(const bf16x8*)(xb0 + j0 + 16);
        xA[2] = *(const bf16x8*)(xb1 + j0);
        xA[3] = *(const bf16x8*)(xb1 + j0 + 16);
    }
    for (int kt = kt0; kt < kt1; ++kt) {
        bf16x8 xB[4];
        if (kt + 1 < kt1) {
            int jn = (kt + 1) * 32;
            xB[0] = *(const bf16x8*)(xb0 + jn);
            xB[1] = *(const bf16x8*)(xb0 + jn + 16);
            xB[2] = *(const bf16x8*)(xb1 + jn);
            xB[3] = *(const bf16x8*)(xb1 + jn + 16);
        }
        int j0 = kt * 32;
        bf16x8 ea[2];
        #pragma unroll
        for (int kk = 0; kk < 2; kk++) {
            unsigned colb = (unsigned)(j0 + kk * 16 + hi * 8) ^ swz;
            u16x8 gv = *(const u16x8*)&gp[colb];
            bf16x8 f;
            #pragma unroll
            for (int e = 0; e < 8; e++) {
                unsigned g = gv[e];
                bool keep = (g != SENT) && (g >= athr || (int)g == agmax);
                float ev = keep ? __expf((float)((int)g - agmax) * (1.0f / 65536.0f)) : 0.f;
                smr += ev;
                f[e] = f2bf(ev);
            }
            ea[kk] = f;
        }
        p0 = __builtin_amdgcn_mfma_f32_32x32x16_bf16(ea[0], xA[0], p0, 0, 0, 0);
        p0 = __builtin_amdgcn_mfma_f32_32x32x16_bf16(ea[1], xA[1], p0, 0, 0, 0);
        p1 = __builtin_amdgcn_mfma_f32_32x32x16_bf16(ea[0], xA[2], p1, 0, 0, 0);
        p1 = __builtin_amdgcn_mfma_f32_32x32x16_bf16(ea[1], xA[3], p1, 0, 0, 0);
        #pragma unroll
        for (int i = 0; i < 4; i++) xA[i] = xB[i];
    }
    smr += __shfl_xor(smr, 32, 64);
    if (lane < 32 && l31 < RT) atomicAdd(&rowsum[l31], smr);
    #pragma unroll
    for (int reg = 0; reg < 16; reg++) {
        int trow = (reg & 3) + 8 * (reg >> 2) + 4 * hi;
        if (trow < RT) {
            atomicAdd(&redf[trow * 65 + l31],      p0[reg]);
            atomicAdd(&redf[trow * 65 + 32 + l31], p1[reg]);
        }
    }
    __syncthreads();

    // ---- epilogue: normalize + residual ----
    for (int i = tid; i < RT * 64; i += 512) {
        int r = i >> 6, d = i & 63;
        int grow = row0 + r;
        if (grow < LL) {
            size_t gi = ((size_t)b * LL + grow) * 64 + d;
            Z[gi] = redf[r * 65 + d] * (1.0f / rowsum[r]) + Xn[gi];
        }
    }
}

// ---------------- Kernel 3: fused LN + FFN + residual ----------------
__global__ __launch_bounds__(256) void k_ffn(
    const float* __restrict__ Zb, const float* __restrict__ fg, const float* __restrict__ fb,
    const float* __restrict__ w1, const float* __restrict__ b1,
    const float* __restrict__ w2, const float* __restrict__ b2,
    float* __restrict__ out)
{
    const int G2 = 16;
    __shared__ float zr[G2][64];
    __shared__ float zl[G2][64];
    __shared__ float h[G2][DHID];
    int tid = threadIdx.x;
    int w = tid >> 6, lane = tid & 63;
    size_t row0 = (size_t)blockIdx.x * G2;
    for (int rr = w; rr < G2; rr += 4) {
        float zv = Zb[(row0 + rr) * 64 + lane];
        zr[rr][lane] = zv;
        float m = zv;
        #pragma unroll
        for (int o = 32; o; o >>= 1) m += __shfl_xor(m, o, 64);
        m *= (1.0f / 64.0f);
        float dv = zv - m;
        float var = dv * dv;
        #pragma unroll
        for (int o = 32; o; o >>= 1) var += __shfl_xor(var, o, 64);
        var *= (1.0f / 64.0f);
        zl[rr][lane] = dv * (1.0f / sqrtf(var + LNEPS)) * fg[lane] + fb[lane];
    }
    __syncthreads();
    float hacc[G2];
    #pragma unroll
    for (int g = 0; g < G2; g++) hacc[g] = 0.f;
    for (int d = 0; d < 64; d++) {
        float wv1 = w1[d * DHID + tid];
        #pragma unroll
        for (int g = 0; g < G2; g++) hacc[g] += zl[g][d] * wv1;
    }
    float b1v = b1[tid];
    #pragma unroll
    for (int g = 0; g < G2; g++) h[g][tid] = fmaxf(hacc[g] + b1v, 0.f);
    __syncthreads();
    float oacc[4] = {0.f, 0.f, 0.f, 0.f};
    for (int i = 0; i < DHID; i++) {
        float wv2 = w2[i * 64 + lane];
        #pragma unroll
        for (int rr = 0; rr < 4; rr++) oacc[rr] += h[w * 4 + rr][i] * wv2;
    }
    float b2v = b2[lane];
    #pragma unroll
    for (int rr = 0; rr < 4; rr++)
        out[(row0 + w * 4 + rr) * 64 + lane] = zr[w * 4 + rr][lane] + oacc[rr] + b2v;
}

extern "C" void kernel_launch(void* const* d_in, const int* in_sizes, int n_in,
                              void* d_out, int out_size, void* d_ws, size_t ws_size,
                              hipStream_t stream)
{
    const float* x      = (const float*)d_in[0];
    const float* stg    = (const float*)d_in[1];
    const float* Wq     = (const float*)d_in[2];
    const float* bq     = (const float*)d_in[3];
    const float* Wk     = (const float*)d_in[4];
    const float* bk     = (const float*)d_in[5];
    const float* gamma  = (const float*)d_in[6];
    const float* beta   = (const float*)d_in[7];
    const float* fgamma = (const float*)d_in[8];
    const float* fbeta  = (const float*)d_in[9];
    const float* w1     = (const float*)d_in[10];
    const float* b1     = (const float*)d_in[11];
    const float* w2     = (const float*)d_in[12];
    const float* b2     = (const float*)d_in[13];
    const int*   topk   = (const int*)d_in[14];
    float* out = (float*)d_out;

    const size_t rows  = (size_t)NBATCH * LL;    // 19872
    const size_t prows = (size_t)NBATCH * LLP;   // 19968
    float* Xn = (float*)d_ws;                    // rows*64 f32
    float* Qb = Xn + rows * 64;                  // (prows+64)*64 f32 (padded + tile-overrun slack)
    float* Z  = Qb + (prows + 64) * 64;          // rows*64 f32
    short* Kbf  = (short*)(Z + rows * 64);       // prows*64 bf16
    short* XbfT = Kbf + prows * 64;              // prows*64 bf16 (transposed layout)
    // total ~20.4 MB — proven ws budget

    k_lnproj<<<(int)(rows / 4), 256, 0, stream>>>(x, Wq, bq, Wk, bk, gamma, beta, Xn, Qb, Kbf);
    k_prep<<<NBATCH * 39, 256, 0, stream>>>(Xn, XbfT, Kbf, Qb);
    k_attn<<<NBATCH * NBLK, 512, 0, stream>>>(Xn, Qb, Kbf, XbfT, stg, topk, Z);
    k_ffn<<<(int)(rows / 16), 256, 0, stream>>>(Z, fgamma, fbeta, w1, b1, w2, b2, out);
}

// Round 15
// 274.822 us; speedup vs baseline: 1.1084x; 1.1084x over previous
//
#include <hip/hip_runtime.h>

#define NBATCH 8
#define NN     207
#define DHID   256
#define LL     2484      // 12*207
#define LLP    2496      // padded to multiple of 32
#define RT     12        // query rows per block (208 blocks/batch)
#define NBLK   208
#define GCOL   2560      // G-tile padded cols (swizzle headroom)
#define ATILES 156       // LLP/16: phase-A j-tiles (16 cols each)
#define CWIN   78        // LLP/32: phase-C k-windows (32 js each)
#define LNEPS  1e-5f

typedef __attribute__((ext_vector_type(8)))  short bf16x8;
typedef __attribute__((ext_vector_type(8)))  unsigned short u16x8;
typedef __attribute__((ext_vector_type(4)))  float f32x4;

__device__ __forceinline__ short f2bf(float f) {
    unsigned u = __float_as_uint(f);
    unsigned r = (u + 0x7FFFu + ((u >> 16) & 1u)) >> 16;
    return (short)r;
}
__device__ __forceinline__ unsigned cvt_pk_bf16(float lo, float hi) {
    unsigned r;
    asm("v_cvt_pk_bf16_f32 %0, %1, %2" : "=v"(r) : "v"(lo), "v"(hi));
    return r;
}

// ---------------- Kernel 1: LayerNorm + Q/K projections ----------------
__global__ __launch_bounds__(256) void k_lnproj(
    const float* __restrict__ x, const float* __restrict__ Wq, const float* __restrict__ bq,
    const float* __restrict__ Wk, const float* __restrict__ bk,
    const float* __restrict__ gamma, const float* __restrict__ beta,
    float* __restrict__ Xn, float* __restrict__ Qb, short* __restrict__ Kbf)
{
    __shared__ float xrow[4][64];
    int w = threadIdx.x >> 6, lane = threadIdx.x & 63;
    size_t row = (size_t)blockIdx.x * 4 + w;
    float xv = x[row * 64 + lane];
    float m = xv;
    #pragma unroll
    for (int o = 32; o; o >>= 1) m += __shfl_xor(m, o, 64);
    m *= (1.0f / 64.0f);
    float dv = xv - m;
    float var = dv * dv;
    #pragma unroll
    for (int o = 32; o; o >>= 1) var += __shfl_xor(var, o, 64);
    var *= (1.0f / 64.0f);
    float xg = dv * (1.0f / sqrtf(var + LNEPS)) * gamma[lane] + beta[lane];
    Xn[row * 64 + lane] = xg;
    xrow[w][lane] = xg;
    __syncthreads();
    float q = bq[lane], k = bk[lane];
    #pragma unroll 8
    for (int e = 0; e < 64; e++) {
        float xe = xrow[w][e];
        q += xe * Wq[e * 64 + lane];
        k += xe * Wk[e * 64 + lane];
    }
    int br = (int)(row / LL);
    int jl = (int)(row - (size_t)br * LL);
    Qb[((size_t)br * LLP + jl) * 64 + lane] = q;
    Kbf[((size_t)br * LLP + jl) * 64 + lane] = f2bf(k);
}

// ---------------- Kernel 1b: transpose Xn -> bf16 X^T, zero all pads ----------------
__global__ __launch_bounds__(256) void k_prep(
    const float* __restrict__ Xn, short* __restrict__ XbfT,
    short* __restrict__ Kbf, float* __restrict__ Qb)
{
    __shared__ float tile[64][65];
    int bb = blockIdx.x & 7;
    int jt = blockIdx.x >> 3;          // 0..38
    int j0 = jt * 64;
    for (int i = threadIdx.x; i < 4096; i += 256) {
        int jl = i >> 6, d = i & 63;
        int j = j0 + jl;
        tile[jl][d] = (j < LL) ? Xn[((size_t)bb * LL + j) * 64 + d] : 0.f;
    }
    __syncthreads();
    for (int i = threadIdx.x; i < 4096; i += 256) {
        int d = i >> 6, jl = i & 63;
        XbfT[((size_t)bb * 64 + d) * LLP + j0 + jl] = f2bf(tile[jl][d]);
    }
    if (jt == 38) {
        for (int i = threadIdx.x; i < (LLP - LL) * 64; i += 256) {
            int jl = i >> 6, d = i & 63;
            Kbf[((size_t)bb * LLP + LL + jl) * 64 + d] = 0;
            Qb [((size_t)bb * LLP + LL + jl) * 64 + d] = 0.f;
        }
    }
}

// ---------------- Kernel 2: fused attn, 16x16 MFMA, e-code select, 2 blocks/CU ----------------
__global__ __launch_bounds__(512, 4) void k_attn(
    const float* __restrict__ Xn, const float* __restrict__ Qb,
    const short* __restrict__ Kbf, const short* __restrict__ XbfT,
    const float* __restrict__ stg, const int* __restrict__ topk_p,
    float* __restrict__ Z)
{
    __shared__ __align__(16) unsigned short Gt[RT * GCOL];   // 61,440 B: bf16(exp(s)) codes
    __shared__ __align__(16) unsigned hist[RT * 256];        // 12,288 B: per-code histogram
    __shared__ unsigned thr_lds[16];
    __shared__ float rsum[16];                               // 1/rowsum (from histogram)
    float* redf = (float*)hist;                              // union: PV accum after scan

    int tid = threadIdx.x;
    int lane = tid & 63, wv = tid >> 6;    // wv in [0,8)
    int q = (lane >> 4) & 3, l15 = lane & 15;
    int b = blockIdx.x & 7;
    int tile = blockIdx.x >> 3;            // 0..207
    int row0 = tile * RT;

    for (int i = tid; i < RT * GCOL / 2; i += 512) ((unsigned*)Gt)[i] = 0u;
    for (int i = tid; i < RT * 256; i += 512) hist[i] = 0u;
    if (tid < 16) { thr_lds[tid] = 0xFFFFu; rsum[tid] = 0.f; }

    int keff;
    { int tk = *topk_p; keff = (tk < 5) ? tk * NN : tk; }

    // Q A-fragments (16x16x32): A row = lane&15, k = q*8+e (+32 for second half)
    bf16x8 qf[2];
    {
        const float* qp = Qb + ((size_t)b * LLP + row0 + l15) * 64 + q * 8;
        #pragma unroll
        for (int h = 0; h < 2; h++) {
            bf16x8 f;
            #pragma unroll
            for (int e = 0; e < 8; e++) f[e] = f2bf(qp[h * 32 + e]);
            qf[h] = f;
        }
    }
    // per output-reg row info (C row = q*4+reg)
    int trow[4]; bool rvalid[4]; int rbase[4];
    #pragma unroll
    for (int r = 0; r < 4; r++) {
        trow[r] = q * 4 + r;
        int grow = row0 + trow[r];
        rvalid[r] = (trow[r] < RT) && (grow < LL);
        rbase[r] = grow * LL;
    }
    const float* stgb = stg + (size_t)b * LL * LL;
    __syncthreads();   // init visible

    // ---- Phase A (double-buffered): MFMA scores -> e=exp(sig*stg) bf16 code -> LDS + hist ----
    float svA[4]; bf16x8 kvA[2];
    {
        int t = wv;
        int j = t * 16 + l15;
        bool jv = (j < LL);
        #pragma unroll
        for (int r = 0; r < 4; r++)
            svA[r] = (jv && rvalid[r]) ? stgb[rbase[r] + j] : 0.f;
        const short* kb = Kbf + ((size_t)b * LLP + j) * 64 + q * 8;
        kvA[0] = *(const bf16x8*)(kb);
        kvA[1] = *(const bf16x8*)(kb + 32);
    }
    for (int t = wv; t < ATILES; t += 8) {
        float svB[4]; bf16x8 kvB[2];
        int tn = t + 8;
        if (tn < ATILES) {
            int jn = tn * 16 + l15;
            bool jv = (jn < LL);
            #pragma unroll
            for (int r = 0; r < 4; r++)
                svB[r] = (jv && rvalid[r]) ? stgb[rbase[r] + jn] : 0.f;
            const short* kb = Kbf + ((size_t)b * LLP + jn) * 64 + q * 8;
            kvB[0] = *(const bf16x8*)(kb);
            kvB[1] = *(const bf16x8*)(kb + 32);
        }
        int j = t * 16 + l15;
        bool vj = (j < LL);
        f32x4 c = {0.f, 0.f, 0.f, 0.f};
        c = __builtin_amdgcn_mfma_f32_16x16x32_bf16(qf[0], kvA[0], c, 0, 0, 0);
        c = __builtin_amdgcn_mfma_f32_16x16x32_bf16(qf[1], kvA[1], c, 0, 0, 0);
        #pragma unroll
        for (int pr = 0; pr < 2; pr++) {
            int r0 = pr * 2, r1 = pr * 2 + 1;
            float sg0 = 1.0f / (1.0f + __expf(c[r0] * -0.125f));
            float e0 = __expf(sg0 * svA[r0]);
            if (!(vj && rvalid[r0])) e0 = 0.f;
            float sg1 = 1.0f / (1.0f + __expf(c[r1] * -0.125f));
            float e1 = __expf(sg1 * svA[r1]);
            if (!(vj && rvalid[r1])) e1 = 0.f;
            unsigned pk = cvt_pk_bf16(e0, e1);
            unsigned b0 = pk & 0xFFFFu, b1 = pk >> 16;
            if (q < 3) {   // trow < RT
                Gt[trow[r0] * GCOL + (j ^ (trow[r0] * 8))] = (unsigned short)b0;
                Gt[trow[r1] * GCOL + (j ^ (trow[r1] * 8))] = (unsigned short)b1;
            }
            if (vj && rvalid[r0]) atomicAdd(&hist[trow[r0] * 256 + ((int)b0 - 0x3F80)], 1u);
            if (vj && rvalid[r1]) atomicAdd(&hist[trow[r1] * 256 + ((int)b1 - 0x3F80)], 1u);
        }
        #pragma unroll
        for (int i2 = 0; i2 < 4; i2++) svA[i2] = svB[i2];
        kvA[0] = kvB[0]; kvA[1] = kvB[1];
    }
    __syncthreads();   // Gt + hist complete

    // ---- Phase B: per-row scan over bf16-code histogram -> threshold + exact row-sum ----
    for (int row = wv; row < RT; row += 8) {
        const unsigned* h = &hist[row * 256];
        unsigned c0 = h[lane * 4 + 0], c1 = h[lane * 4 + 1];
        unsigned c2 = h[lane * 4 + 2], c3 = h[lane * 4 + 3];
        unsigned S = c0 + c1 + c2 + c3;
        unsigned T = S;
        #pragma unroll
        for (int off = 1; off < 64; off <<= 1) {
            unsigned tt = __shfl_down(T, off, 64);
            T += (lane + off < 64) ? tt : 0u;
        }
        unsigned Tn = T - S;
        unsigned s3 = c3 + Tn, s2 = c2 + s3, s1 = c1 + s2, s0 = c0 + s1;
        unsigned kr = (unsigned)keff;
        int hit = -1; unsigned nk = 0, mm = 0;
        if (s3 >= kr && Tn < kr) { hit = 3; nk = kr - Tn; mm = c3; }
        if (s2 >= kr && s3 < kr) { hit = 2; nk = kr - s3; mm = c2; }
        if (s1 >= kr && s2 < kr) { hit = 1; nk = kr - s2; mm = c1; }
        if (s0 >= kr && s1 < kr) { hit = 0; nk = kr - s1; mm = c0; }
        unsigned long long mask = __ballot(hit >= 0);
        int selBin = 100000, dropi = 0;
        if (mask != 0ull) {
            int src = __ffsll(mask) - 1;
            int bini = __shfl(hit, src, 64);
            unsigned nks = (unsigned)__shfl((int)nk, src, 64);
            unsigned mms = (unsigned)__shfl((int)mm, src, 64);
            selBin = src * 4 + bini;
            dropi = (2u * nks <= mms && nks < kr) ? 1 : 0;   // balanced edge, never empty
        }
        float part = 0.f;
        unsigned cnts[4] = {c0, c1, c2, c3};
        #pragma unroll
        for (int i = 0; i < 4; i++) {
            int bi = lane * 4 + i;
            bool keep = (bi > selBin) || (bi == selBin && dropi == 0);
            if (keep && cnts[i])
                part += (float)cnts[i] * __uint_as_float((unsigned)(0x3F80 + bi) << 16);
        }
        #pragma unroll
        for (int off = 1; off < 64; off <<= 1) part += __shfl_xor(part, off, 64);
        if (lane == 0) {
            thr_lds[row] = (mask == 0ull) ? 0xFFFFu : (unsigned)(0x3F80 + selBin + dropi);
            rsum[row] = (part > 0.f) ? (1.0f / part) : 0.f;
        }
    }
    __syncthreads();   // scan done reading hist

    for (int i = tid; i < RT * 65; i += 512) redf[i] = 0.f;
    __syncthreads();

    // ---- Phase C (double-buffered): PV from Gt codes (compare+select only, no exp) ----
    int arow = (l15 < RT) ? l15 : 0;
    unsigned athr = (l15 < RT) ? thr_lds[l15] : 0xFFFFu;
    const unsigned short* gp = &Gt[arow * GCOL];
    unsigned aswz = (unsigned)(arow * 8);
    const short* xb = XbfT + ((size_t)b * 64 + l15) * LLP + q * 8;
    f32x4 p0 = {0.f, 0.f, 0.f, 0.f}, p1 = p0, p2 = p0, p3 = p0;
    bf16x8 xA0, xA1, xA2, xA3;
    {
        int j0 = wv * 32;
        xA0 = *(const bf16x8*)(xb + j0);
        xA1 = *(const bf16x8*)(xb + 16 * LLP + j0);
        xA2 = *(const bf16x8*)(xb + 32 * LLP + j0);
        xA3 = *(const bf16x8*)(xb + 48 * LLP + j0);
    }
    for (int kw = wv; kw < CWIN; kw += 8) {
        bf16x8 xB0, xB1, xB2, xB3;
        int kn = kw + 8;
        if (kn < CWIN) {
            int jn = kn * 32;
            xB0 = *(const bf16x8*)(xb + jn);
            xB1 = *(const bf16x8*)(xb + 16 * LLP + jn);
            xB2 = *(const bf16x8*)(xb + 32 * LLP + jn);
            xB3 = *(const bf16x8*)(xb + 48 * LLP + jn);
        }
        int j0 = kw * 32;
        u16x8 gv = *(const u16x8*)&gp[(unsigned)(j0 + q * 8) ^ aswz];
        bf16x8 ea;
        #pragma unroll
        for (int e = 0; e < 8; e++) {
            unsigned g = gv[e];
            ea[e] = (g >= athr) ? (short)g : (short)0;
        }
        p0 = __builtin_amdgcn_mfma_f32_16x16x32_bf16(ea, xA0, p0, 0, 0, 0);
        p1 = __builtin_amdgcn_mfma_f32_16x16x32_bf16(ea, xA1, p1, 0, 0, 0);
        p2 = __builtin_amdgcn_mfma_f32_16x16x32_bf16(ea, xA2, p2, 0, 0, 0);
        p3 = __builtin_amdgcn_mfma_f32_16x16x32_bf16(ea, xA3, p3, 0, 0, 0);
        xA0 = xB0; xA1 = xB1; xA2 = xB2; xA3 = xB3;
    }
    if (q < 3) {   // trow < RT
        #pragma unroll
        for (int r = 0; r < 4; r++) {
            atomicAdd(&redf[trow[r] * 65 +      l15], p0[r]);
            atomicAdd(&redf[trow[r] * 65 + 16 + l15], p1[r]);
            atomicAdd(&redf[trow[r] * 65 + 32 + l15], p2[r]);
            atomicAdd(&redf[trow[r] * 65 + 48 + l15], p3[r]);
        }
    }
    __syncthreads();

    // ---- epilogue: normalize + residual ----
    for (int i = tid; i < RT * 64; i += 512) {
        int r = i >> 6, d = i & 63;
        int grow = row0 + r;
        if (grow < LL) {
            size_t gi = ((size_t)b * LL + grow) * 64 + d;
            Z[gi] = redf[r * 65 + d] * rsum[r] + Xn[gi];
        }
    }
}

// ---------------- Kernel 3: fused LN + FFN + residual ----------------
__global__ __launch_bounds__(256) void k_ffn(
    const float* __restrict__ Zb, const float* __restrict__ fg, const float* __restrict__ fb,
    const float* __restrict__ w1, const float* __restrict__ b1,
    const float* __restrict__ w2, const float* __restrict__ b2,
    float* __restrict__ out)
{
    const int G2 = 16;
    __shared__ float zr[G2][64];
    __shared__ float zl[G2][64];
    __shared__ float h[G2][DHID];
    int tid = threadIdx.x;
    int w = tid >> 6, lane = tid & 63;
    size_t row0 = (size_t)blockIdx.x * G2;
    for (int rr = w; rr < G2; rr += 4) {
        float zv = Zb[(row0 + rr) * 64 + lane];
        zr[rr][lane] = zv;
        float m = zv;
        #pragma unroll
        for (int o = 32; o; o >>= 1) m += __shfl_xor(m, o, 64);
        m *= (1.0f / 64.0f);
        float dv = zv - m;
        float var = dv * dv;
        #pragma unroll
        for (int o = 32; o; o >>= 1) var += __shfl_xor(var, o, 64);
        var *= (1.0f / 64.0f);
        zl[rr][lane] = dv * (1.0f / sqrtf(var + LNEPS)) * fg[lane] + fb[lane];
    }
    __syncthreads();
    float hacc[G2];
    #pragma unroll
    for (int g = 0; g < G2; g++) hacc[g] = 0.f;
    for (int d = 0; d < 64; d++) {
        float wv1 = w1[d * DHID + tid];
        #pragma unroll
        for (int g = 0; g < G2; g++) hacc[g] += zl[g][d] * wv1;
    }
    float b1v = b1[tid];
    #pragma unroll
    for (int g = 0; g < G2; g++) h[g][tid] = fmaxf(hacc[g] + b1v, 0.f);
    __syncthreads();
    float oacc[4] = {0.f, 0.f, 0.f, 0.f};
    for (int i = 0; i < DHID; i++) {
        float wv2 = w2[i * 64 + lane];
        #pragma unroll
        for (int rr = 0; rr < 4; rr++) oacc[rr] += h[w * 4 + rr][i] * wv2;
    }
    float b2v = b2[lane];
    #pragma unroll
    for (int rr = 0; rr < 4; rr++)
        out[(row0 + w * 4 + rr) * 64 + lane] = zr[w * 4 + rr][lane] + oacc[rr] + b2v;
}

extern "C" void kernel_launch(void* const* d_in, const int* in_sizes, int n_in,
                              void* d_out, int out_size, void* d_ws, size_t ws_size,
                              hipStream_t stream)
{
    const float* x      = (const float*)d_in[0];
    const float* stg    = (const float*)d_in[1];
    const float* Wq     = (const float*)d_in[2];
    const float* bq     = (const float*)d_in[3];
    const float* Wk     = (const float*)d_in[4];
    const float* bk     = (const float*)d_in[5];
    const float* gamma  = (const float*)d_in[6];
    const float* beta   = (const float*)d_in[7];
    const float* fgamma = (const float*)d_in[8];
    const float* fbeta  = (const float*)d_in[9];
    const float* w1     = (const float*)d_in[10];
    const float* b1     = (const float*)d_in[11];
    const float* w2     = (const float*)d_in[12];
    const float* b2     = (const float*)d_in[13];
    const int*   topk   = (const int*)d_in[14];
    float* out = (float*)d_out;

    const size_t rows  = (size_t)NBATCH * LL;    // 19872
    const size_t prows = (size_t)NBATCH * LLP;   // 19968
    float* Xn = (float*)d_ws;                    // rows*64 f32
    float* Qb = Xn + rows * 64;                  // (prows+64)*64 f32 (padded + tile-overrun slack)
    float* Z  = Qb + (prows + 64) * 64;          // rows*64 f32
    short* Kbf  = (short*)(Z + rows * 64);       // prows*64 bf16
    short* XbfT = Kbf + prows * 64;              // prows*64 bf16 (transposed layout)
    // total ~20.4 MB — proven ws budget

    k_lnproj<<<(int)(rows / 4), 256, 0, stream>>>(x, Wq, bq, Wk, bk, gamma, beta, Xn, Qb, Kbf);
    k_prep<<<NBATCH * 39, 256, 0, stream>>>(Xn, XbfT, Kbf, Qb);
    k_attn<<<NBATCH * NBLK, 512, 0, stream>>>(Xn, Qb, Kbf, XbfT, stg, topk, Z);
    k_ffn<<<(int)(rows / 16), 256, 0, stream>>>(Z, fgamma, fbeta, w1, b1, w2, b2, out);
}

// Round 16
// 250.853 us; speedup vs baseline: 1.2143x; 1.0956x over previous
//
#include <hip/hip_runtime.h>

#define NBATCH 8
#define NN     207
#define DHID   256
#define LL     2484      // 12*207
#define LLP    2496      // padded to multiple of 32
#define RT     26        // query rows per block (96 blocks/batch: 96*26=2496)
#define NBLK   96
#define GCOL   2560      // G-tile padded cols (swizzle headroom)
#define TILES  78        // LLP/32
#define TPW    10        // j-tiles per wave (8 waves x 10 >= 78)
#define SENT   0xFFFFu
#define LNEPS  1e-5f

typedef __attribute__((ext_vector_type(8)))  short bf16x8;
typedef __attribute__((ext_vector_type(8)))  unsigned short u16x8;
typedef __attribute__((ext_vector_type(16))) float f32x16;

__device__ __forceinline__ short f2bf(float f) {
    unsigned u = __float_as_uint(f);
    unsigned r = (u + 0x7FFFu + ((u >> 16) & 1u)) >> 16;
    return (short)r;
}

// ---------------- Kernel 1: LayerNorm + Q/K projections ----------------
__global__ __launch_bounds__(256) void k_lnproj(
    const float* __restrict__ x, const float* __restrict__ Wq, const float* __restrict__ bq,
    const float* __restrict__ Wk, const float* __restrict__ bk,
    const float* __restrict__ gamma, const float* __restrict__ beta,
    float* __restrict__ Xn, float* __restrict__ Qb, short* __restrict__ Kbf)
{
    __shared__ float xrow[4][64];
    int w = threadIdx.x >> 6, lane = threadIdx.x & 63;
    size_t row = (size_t)blockIdx.x * 4 + w;
    float xv = x[row * 64 + lane];
    float m = xv;
    #pragma unroll
    for (int o = 32; o; o >>= 1) m += __shfl_xor(m, o, 64);
    m *= (1.0f / 64.0f);
    float dv = xv - m;
    float var = dv * dv;
    #pragma unroll
    for (int o = 32; o; o >>= 1) var += __shfl_xor(var, o, 64);
    var *= (1.0f / 64.0f);
    float xg = dv * (1.0f / sqrtf(var + LNEPS)) * gamma[lane] + beta[lane];
    Xn[row * 64 + lane] = xg;
    xrow[w][lane] = xg;
    __syncthreads();
    float q = bq[lane], k = bk[lane];
    #pragma unroll 8
    for (int e = 0; e < 64; e++) {
        float xe = xrow[w][e];
        q += xe * Wq[e * 64 + lane];
        k += xe * Wk[e * 64 + lane];
    }
    int br = (int)(row / LL);
    int jl = (int)(row - (size_t)br * LL);
    Qb[((size_t)br * LLP + jl) * 64 + lane] = q;
    Kbf[((size_t)br * LLP + jl) * 64 + lane] = f2bf(k);
}

// ---------------- Kernel 1b: transpose Xn -> bf16 X^T, zero all pads ----------------
__global__ __launch_bounds__(256) void k_prep(
    const float* __restrict__ Xn, short* __restrict__ XbfT,
    short* __restrict__ Kbf, float* __restrict__ Qb)
{
    __shared__ float tile[64][65];
    int bb = blockIdx.x & 7;
    int jt = blockIdx.x >> 3;          // 0..38
    int j0 = jt * 64;
    for (int i = threadIdx.x; i < 4096; i += 256) {
        int jl = i >> 6, d = i & 63;
        int j = j0 + jl;
        tile[jl][d] = (j < LL) ? Xn[((size_t)bb * LL + j) * 64 + d] : 0.f;
    }
    __syncthreads();
    for (int i = threadIdx.x; i < 4096; i += 256) {
        int d = i >> 6, jl = i & 63;
        XbfT[((size_t)bb * 64 + d) * LLP + j0 + jl] = f2bf(tile[jl][d]);
    }
    if (jt == 38) {
        for (int i = threadIdx.x; i < (LLP - LL) * 64; i += 256) {
            int jl = i >> 6, d = i & 63;
            Kbf[((size_t)bb * LLP + LL + jl) * 64 + d] = 0;
            Qb [((size_t)bb * LLP + LL + jl) * 64 + d] = 0.f;
        }
    }
}

// ---- Phase-A helpers: static-indexed staging (rule #20: named buffers only) ----
__device__ __forceinline__ void loadA(
    float (&sv)[16], bf16x8 (&kv)[4], int kt,
    int l31, int hi, int row0, int b,
    const float* __restrict__ stgb, const short* __restrict__ Kbf)
{
    int j = kt * 32 + l31;
    #pragma unroll
    for (int reg = 0; reg < 16; reg++) {
        int trow = (reg & 3) + 8 * (reg >> 2) + 4 * hi;
        int grow = row0 + trow;
        bool v = (j < LL) && (trow < RT) && (grow < LL);
        sv[reg] = v ? stgb[(size_t)grow * LL + j] : 0.f;
    }
    const short* kb = Kbf + ((size_t)b * LLP + j) * 64 + hi * 8;
    kv[0] = *(const bf16x8*)(kb);
    kv[1] = *(const bf16x8*)(kb + 16);
    kv[2] = *(const bf16x8*)(kb + 32);
    kv[3] = *(const bf16x8*)(kb + 48);
}

__device__ __forceinline__ void computeA(
    const float (&sv)[16], const bf16x8 (&kv)[4], int kt,
    const bf16x8 (&qf)[4], int (&gmx)[16],
    int l31, int hi, int row0,
    unsigned short* __restrict__ Gt_, unsigned* __restrict__ hist_)
{
    int j = kt * 32 + l31;
    bool vj = (j < LL);
    f32x16 c = {0.f,0.f,0.f,0.f,0.f,0.f,0.f,0.f,0.f,0.f,0.f,0.f,0.f,0.f,0.f,0.f};
    c = __builtin_amdgcn_mfma_f32_32x32x16_bf16(qf[0], kv[0], c, 0, 0, 0);
    c = __builtin_amdgcn_mfma_f32_32x32x16_bf16(qf[1], kv[1], c, 0, 0, 0);
    c = __builtin_amdgcn_mfma_f32_32x32x16_bf16(qf[2], kv[2], c, 0, 0, 0);
    c = __builtin_amdgcn_mfma_f32_32x32x16_bf16(qf[3], kv[3], c, 0, 0, 0);
    #pragma unroll
    for (int reg = 0; reg < 16; reg++) {
        int trow = (reg & 3) + 8 * (reg >> 2) + 4 * hi;
        int grow = row0 + trow;
        bool v = vj && (trow < RT) && (grow < LL);
        float sg = 1.0f / (1.0f + __expf(c[reg] * -0.125f));
        float s = sg * sv[reg];
        int g = (int)(s * 65536.0f); g = (g > 65534) ? 65534 : g;
        if (v) {
            unsigned col = (unsigned)j ^ ((unsigned)(trow & 15) << 3);
            Gt_[trow * GCOL + col] = (unsigned short)g;
            atomicAdd(&hist_[trow * 256 + (g >> 8)], 1u << (((g >> 7) & 1) << 4));
            gmx[reg] = (g > gmx[reg]) ? g : gmx[reg];
        }
    }
}

// ---------------- Kernel 2: fused attn, 512 thr, G in LDS, 3-buffer pipelined ----------------
__global__ __launch_bounds__(512, 2) void k_attn(
    const float* __restrict__ Xn, const float* __restrict__ Qb,
    const short* __restrict__ Kbf, const short* __restrict__ XbfT,
    const float* __restrict__ stg, const int* __restrict__ topk_p,
    float* __restrict__ Z)
{
    __shared__ __align__(16) unsigned short Gt[RT * GCOL];   // 133,120 B
    __shared__ __align__(16) unsigned hist[RT * 256];        // 26,624 B (512-bin packed u16x2)
    __shared__ int gmax_lds[RT];
    __shared__ unsigned thr_lds[RT];
    float* redf = (float*)hist;            // union: red[RT*65] + rowsum[RT], hist dead after scan
    float* rowsum = redf + RT * 65;

    int tid = threadIdx.x;
    int lane = tid & 63, wv = tid >> 6;    // wv in [0,8)
    int hi = lane >> 5, l31 = lane & 31;
    int b = blockIdx.x & 7;
    int tile = blockIdx.x >> 3;            // 0..95
    int row0 = tile * RT;

    // ---- init: Gt = sentinel, hist = 0, gmax = 0 ----
    for (int i = tid; i < RT * GCOL / 2; i += 512) ((unsigned*)Gt)[i] = 0xFFFFFFFFu;
    for (int i = tid; i < RT * 256; i += 512) hist[i] = 0u;
    if (tid < RT) gmax_lds[tid] = 0;

    int keff;
    { int tk = *topk_p; keff = (tk < 5) ? tk * NN : tk; }

    // Q A-fragments: row = row0 + l31 (rows >= RT give garbage -> discarded downstream)
    bf16x8 qf[4];
    {
        const float* qp = Qb + ((size_t)b * LLP + row0 + l31) * 64 + hi * 8;
        #pragma unroll
        for (int kk = 0; kk < 4; kk++) {
            bf16x8 f;
            #pragma unroll
            for (int e = 0; e < 8; e++) f[e] = f2bf(qp[kk * 16 + e]);
            qf[kk] = f;
        }
    }
    const float* stgb = stg + (size_t)b * LL * LL;
    int kt0 = wv * TPW;
    int kt1 = (kt0 + TPW < TILES) ? kt0 + TPW : TILES;
    __syncthreads();   // init visible

    // ---- Phase A: 3-buffer rotation, loads issued 2 compute-phases ahead ----
    int gmx[16];
    #pragma unroll
    for (int i = 0; i < 16; i++) gmx[i] = 0;

    {
        float sv0[16], sv1[16], sv2[16];
        bf16x8 kv0[4], kv1[4], kv2[4];
        loadA(sv0, kv0, kt0, l31, hi, row0, b, stgb, Kbf);
        if (kt0 + 1 < kt1) loadA(sv1, kv1, kt0 + 1, l31, hi, row0, b, stgb, Kbf);
        int kt = kt0;
        while (kt < kt1) {
            if (kt + 2 < kt1) loadA(sv2, kv2, kt + 2, l31, hi, row0, b, stgb, Kbf);
            computeA(sv0, kv0, kt, qf, gmx, l31, hi, row0, Gt, hist);
            if (kt + 1 >= kt1) break;
            if (kt + 3 < kt1) loadA(sv0, kv0, kt + 3, l31, hi, row0, b, stgb, Kbf);
            computeA(sv1, kv1, kt + 1, qf, gmx, l31, hi, row0, Gt, hist);
            if (kt + 2 >= kt1) break;
            if (kt + 4 < kt1) loadA(sv1, kv1, kt + 4, l31, hi, row0, b, stgb, Kbf);
            computeA(sv2, kv2, kt + 2, qf, gmx, l31, hi, row0, Gt, hist);
            kt += 3;
        }
    }
    #pragma unroll
    for (int reg = 0; reg < 16; reg++) {
        int v = gmx[reg];
        #pragma unroll
        for (int off = 1; off < 32; off <<= 1) {
            int o2 = __shfl_xor(v, off, 64);
            v = (o2 > v) ? o2 : v;
        }
        if (l31 == 0) {
            int trow = (reg & 3) + 8 * (reg >> 2) + 4 * hi;
            if (trow < RT) atomicMax(&gmax_lds[trow], v);
        }
    }
    __syncthreads();   // Gt + hist + gmax complete

    // ---- Phase B: 512-bin scan per row -> threshold (keep g >= thrge) ----
    #pragma unroll 1
    for (int row = wv; row < RT; row += 8) {
        const unsigned* h = &hist[row * 256];
        unsigned w0 = h[lane * 4 + 0], w1 = h[lane * 4 + 1];
        unsigned w2 = h[lane * 4 + 2], w3 = h[lane * 4 + 3];
        unsigned cb[8] = {w0 & 0xFFFFu, w0 >> 16, w1 & 0xFFFFu, w1 >> 16,
                          w2 & 0xFFFFu, w2 >> 16, w3 & 0xFFFFu, w3 >> 16};
        unsigned S = cb[0] + cb[1] + cb[2] + cb[3] + cb[4] + cb[5] + cb[6] + cb[7];
        unsigned T = S;
        #pragma unroll
        for (int off = 1; off < 64; off <<= 1) {
            unsigned t = __shfl_down(T, off, 64);
            T += (lane + off < 64) ? t : 0u;
        }
        unsigned Tn = T - S;
        unsigned sfx[9];
        sfx[8] = Tn;
        #pragma unroll
        for (int i = 7; i >= 0; i--) sfx[i] = cb[i] + sfx[i + 1];
        unsigned kr = (unsigned)keff;
        int hit = -1; unsigned nk = 0, mm = 0;
        #pragma unroll
        for (int i = 0; i < 8; i++) {
            if (sfx[i] >= kr && sfx[i + 1] < kr) { hit = i; nk = kr - sfx[i + 1]; mm = cb[i]; }
        }
        unsigned long long mask = __ballot(hit >= 0);
        if (mask == 0ull) {
            if (lane == 0) thr_lds[row] = 65535u;
        } else {
            int src = __ffsll(mask) - 1;
            int bini = __shfl(hit, src, 64);
            nk = (unsigned)__shfl((int)nk, src, 64);
            mm = (unsigned)__shfl((int)mm, src, 64);
            if (lane == 0) {
                int bin = src * 8 + bini;
                int drop = (2u * nk <= mm) ? 1 : 0;
                int thrge = bin * 128 + (drop ? 128 : 0);
                if (thrge > 65535) thrge = 65535;
                thr_lds[row] = (unsigned)thrge;
            }
        }
    }
    __syncthreads();   // scans done reading hist

    // ---- re-purpose hist region as PV accumulators ----
    for (int i = tid; i < RT * 65 + RT; i += 512) redf[i] = 0.f;
    __syncthreads();

    // ---- Phase C: ping-pong double buffer (copy-free), PV from LDS G-tile ----
    bool av = (l31 < RT);
    int arow = av ? l31 : 0;
    int agmax = av ? gmax_lds[arow] : -1;
    unsigned athr = av ? thr_lds[arow] : 65535u;
    unsigned swz = ((unsigned)(arow & 15)) << 3;
    const unsigned short* gp = &Gt[arow * GCOL];
    const short* xb0 = XbfT + ((size_t)b * 64 + l31) * LLP + hi * 8;
    const short* xb1 = XbfT + ((size_t)b * 64 + 32 + l31) * LLP + hi * 8;
    f32x16 p0 = {0.f,0.f,0.f,0.f,0.f,0.f,0.f,0.f,0.f,0.f,0.f,0.f,0.f,0.f,0.f,0.f};
    f32x16 p1 = p0;
    float smr = 0.f;

    {
        bf16x8 xA[4], xB[4];
        if (kt0 < kt1) {
            int j0 = kt0 * 32;
            xA[0] = *(const bf16x8*)(xb0 + j0);
            xA[1] = *(const bf16x8*)(xb0 + j0 + 16);
            xA[2] = *(const bf16x8*)(xb1 + j0);
            xA[3] = *(const bf16x8*)(xb1 + j0 + 16);
        }
        if (kt0 + 1 < kt1) {
            int j0 = (kt0 + 1) * 32;
            xB[0] = *(const bf16x8*)(xb0 + j0);
            xB[1] = *(const bf16x8*)(xb0 + j0 + 16);
            xB[2] = *(const bf16x8*)(xb1 + j0);
            xB[3] = *(const bf16x8*)(xb1 + j0 + 16);
        }
        int kt = kt0;
        while (kt < kt1) {
            // compute with xA at kt
            {
                int j0 = kt * 32;
                bf16x8 ea[2];
                #pragma unroll
                for (int kk = 0; kk < 2; kk++) {
                    unsigned colb = (unsigned)(j0 + kk * 16 + hi * 8) ^ swz;
                    u16x8 gv = *(const u16x8*)&gp[colb];
                    bf16x8 f;
                    #pragma unroll
                    for (int e = 0; e < 8; e++) {
                        unsigned g = gv[e];
                        bool keep = (g != SENT) && (g >= athr || (int)g == agmax);
                        float ev = keep ? __expf((float)((int)g - agmax) * (1.0f / 65536.0f)) : 0.f;
                        smr += ev;
                        f[e] = f2bf(ev);
                    }
                    ea[kk] = f;
                }
                p0 = __builtin_amdgcn_mfma_f32_32x32x16_bf16(ea[0], xA[0], p0, 0, 0, 0);
                p0 = __builtin_amdgcn_mfma_f32_32x32x16_bf16(ea[1], xA[1], p0, 0, 0, 0);
                p1 = __builtin_amdgcn_mfma_f32_32x32x16_bf16(ea[0], xA[2], p1, 0, 0, 0);
                p1 = __builtin_amdgcn_mfma_f32_32x32x16_bf16(ea[1], xA[3], p1, 0, 0, 0);
            }
            if (kt + 2 < kt1) {
                int j0 = (kt + 2) * 32;
                xA[0] = *(const bf16x8*)(xb0 + j0);
                xA[1] = *(const bf16x8*)(xb0 + j0 + 16);
                xA[2] = *(const bf16x8*)(xb1 + j0);
                xA[3] = *(const bf16x8*)(xb1 + j0 + 16);
            }
            if (kt + 1 >= kt1) break;
            // compute with xB at kt+1
            {
                int j0 = (kt + 1) * 32;
                bf16x8 ea[2];
                #pragma unroll
                for (int kk = 0; kk < 2; kk++) {
                    unsigned colb = (unsigned)(j0 + kk * 16 + hi * 8) ^ swz;
                    u16x8 gv = *(const u16x8*)&gp[colb];
                    bf16x8 f;
                    #pragma unroll
                    for (int e = 0; e < 8; e++) {
                        unsigned g = gv[e];
                        bool keep = (g != SENT) && (g >= athr || (int)g == agmax);
                        float ev = keep ? __expf((float)((int)g - agmax) * (1.0f / 65536.0f)) : 0.f;
                        smr += ev;
                        f[e] = f2bf(ev);
                    }
                    ea[kk] = f;
                }
                p0 = __builtin_amdgcn_mfma_f32_32x32x16_bf16(ea[0], xB[0], p0, 0, 0, 0);
                p0 = __builtin_amdgcn_mfma_f32_32x32x16_bf16(ea[1], xB[1], p0, 0, 0, 0);
                p1 = __builtin_amdgcn_mfma_f32_32x32x16_bf16(ea[0], xB[2], p1, 0, 0, 0);
                p1 = __builtin_amdgcn_mfma_f32_32x32x16_bf16(ea[1], xB[3], p1, 0, 0, 0);
            }
            if (kt + 3 < kt1) {
                int j0 = (kt + 3) * 32;
                xB[0] = *(const bf16x8*)(xb0 + j0);
                xB[1] = *(const bf16x8*)(xb0 + j0 + 16);
                xB[2] = *(const bf16x8*)(xb1 + j0);
                xB[3] = *(const bf16x8*)(xb1 + j0 + 16);
            }
            kt += 2;
        }
    }
    smr += __shfl_xor(smr, 32, 64);
    if (lane < 32 && l31 < RT) atomicAdd(&rowsum[l31], smr);
    #pragma unroll
    for (int reg = 0; reg < 16; reg++) {
        int trow = (reg & 3) + 8 * (reg >> 2) + 4 * hi;
        if (trow < RT) {
            atomicAdd(&redf[trow * 65 + l31],      p0[reg]);
            atomicAdd(&redf[trow * 65 + 32 + l31], p1[reg]);
        }
    }
    __syncthreads();

    // ---- epilogue: normalize + residual ----
    for (int i = tid; i < RT * 64; i += 512) {
        int r = i >> 6, d = i & 63;
        int grow = row0 + r;
        if (grow < LL) {
            size_t gi = ((size_t)b * LL + grow) * 64 + d;
            Z[gi] = redf[r * 65 + d] * (1.0f / rowsum[r]) + Xn[gi];
        }
    }
}

// ---------------- Kernel 3: fused LN + FFN + residual ----------------
__global__ __launch_bounds__(256) void k_ffn(
    const float* __restrict__ Zb, const float* __restrict__ fg, const float* __restrict__ fb,
    const float* __restrict__ w1, const float* __restrict__ b1,
    const float* __restrict__ w2, const float* __restrict__ b2,
    float* __restrict__ out)
{
    const int G2 = 16;
    __shared__ float zr[G2][64];
    __shared__ float zl[G2][64];
    __shared__ float h[G2][DHID];
    int tid = threadIdx.x;
    int w = tid >> 6, lane = tid & 63;
    size_t row0 = (size_t)blockIdx.x * G2;
    for (int rr = w; rr < G2; rr += 4) {
        float zv = Zb[(row0 + rr) * 64 + lane];
        zr[rr][lane] = zv;
        float m = zv;
        #pragma unroll
        for (int o = 32; o; o >>= 1) m += __shfl_xor(m, o, 64);
        m *= (1.0f / 64.0f);
        float dv = zv - m;
        float var = dv * dv;
        #pragma unroll
        for (int o = 32; o; o >>= 1) var += __shfl_xor(var, o, 64);
        var *= (1.0f / 64.0f);
        zl[rr][lane] = dv * (1.0f / sqrtf(var + LNEPS)) * fg[lane] + fb[lane];
    }
    __syncthreads();
    float hacc[G2];
    #pragma unroll
    for (int g = 0; g < G2; g++) hacc[g] = 0.f;
    for (int d = 0; d < 64; d++) {
        float wv1 = w1[d * DHID + tid];
        #pragma unroll
        for (int g = 0; g < G2; g++) hacc[g] += zl[g][d] * wv1;
    }
    float b1v = b1[tid];
    #pragma unroll
    for (int g = 0; g < G2; g++) h[g][tid] = fmaxf(hacc[g] + b1v, 0.f);
    __syncthreads();
    float oacc[4] = {0.f, 0.f, 0.f, 0.f};
    for (int i = 0; i < DHID; i++) {
        float wv2 = w2[i * 64 + lane];
        #pragma unroll
        for (int rr = 0; rr < 4; rr++) oacc[rr] += h[w * 4 + rr][i] * wv2;
    }
    float b2v = b2[lane];
    #pragma unroll
    for (int rr = 0; rr < 4; rr++)
        out[(row0 + w * 4 + rr) * 64 + lane] = zr[w * 4 + rr][lane] + oacc[rr] + b2v;
}

extern "C" void kernel_launch(void* const* d_in, const int* in_sizes, int n_in,
                              void* d_out, int out_size, void* d_ws, size_t ws_size,
                              hipStream_t stream)
{
    const float* x      = (const float*)d_in[0];
    const float* stg    = (const float*)d_in[1];
    const float* Wq     = (const float*)d_in[2];
    const float* bq     = (const float*)d_in[3];
    const float* Wk     = (const float*)d_in[4];
    const float* bk     = (const float*)d_in[5];
    const float* gamma  = (const float*)d_in[6];
    const float* beta   = (const float*)d_in[7];
    const float* fgamma = (const float*)d_in[8];
    const float* fbeta  = (const float*)d_in[9];
    const float* w1     = (const float*)d_in[10];
    const float* b1     = (const float*)d_in[11];
    const float* w2     = (const float*)d_in[12];
    const float* b2     = (const float*)d_in[13];
    const int*   topk   = (const int*)d_in[14];
    float* out = (float*)d_out;

    const size_t rows  = (size_t)NBATCH * LL;    // 19872
    const size_t prows = (size_t)NBATCH * LLP;   // 19968
    float* Xn = (float*)d_ws;                    // rows*64 f32
    float* Qb = Xn + rows * 64;                  // (prows+64)*64 f32 (padded + tile-overrun slack)
    float* Z  = Qb + (prows + 64) * 64;          // rows*64 f32
    short* Kbf  = (short*)(Z + rows * 64);       // prows*64 bf16
    short* XbfT = Kbf + prows * 64;              // prows*64 bf16 (transposed layout)
    // total ~20.4 MB — proven ws budget

    k_lnproj<<<(int)(rows / 4), 256, 0, stream>>>(x, Wq, bq, Wk, bk, gamma, beta, Xn, Qb, Kbf);
    k_prep<<<NBATCH * 39, 256, 0, stream>>>(Xn, XbfT, Kbf, Qb);
    k_attn<<<NBATCH * NBLK, 512, 0, stream>>>(Xn, Qb, Kbf, XbfT, stg, topk, Z);
    k_ffn<<<(int)(rows / 16), 256, 0, stream>>>(Z, fgamma, fbeta, w1, b1, w2, b2, out);
}

// Round 18
// 248.912 us; speedup vs baseline: 1.2237x; 1.0078x over previous
//
#include <hip/hip_runtime.h>

#define NBATCH 8
#define NN     207
#define DHID   256
#define LL     2484      // 12*207
#define LLP    2496      // padded to multiple of 32
#define RT     26        // query rows per block (96 blocks/batch: 96*26=2496)
#define NBLK   96
#define GCOL   2560      // G-tile padded cols (swizzle headroom)
#define TILES  78        // LLP/32
#define TPW    10        // j-tiles per wave (8 waves x 10 >= 78)
#define SENT   0xFFFFu
#define LNEPS  1e-5f

typedef __attribute__((ext_vector_type(8)))  short bf16x8;
typedef __attribute__((ext_vector_type(8)))  unsigned short u16x8;
typedef __attribute__((ext_vector_type(16))) float f32x16;

__device__ __forceinline__ short f2bf(float f) {
    unsigned u = __float_as_uint(f);
    unsigned r = (u + 0x7FFFu + ((u >> 16) & 1u)) >> 16;
    return (short)r;
}

// ---------------- Kernel 1: LayerNorm + Q/K projections ----------------
__global__ __launch_bounds__(256) void k_lnproj(
    const float* __restrict__ x, const float* __restrict__ Wq, const float* __restrict__ bq,
    const float* __restrict__ Wk, const float* __restrict__ bk,
    const float* __restrict__ gamma, const float* __restrict__ beta,
    float* __restrict__ Xn, float* __restrict__ Qb, short* __restrict__ Kbf)
{
    __shared__ float xrow[4][64];
    int w = threadIdx.x >> 6, lane = threadIdx.x & 63;
    size_t row = (size_t)blockIdx.x * 4 + w;
    float xv = x[row * 64 + lane];
    float m = xv;
    #pragma unroll
    for (int o = 32; o; o >>= 1) m += __shfl_xor(m, o, 64);
    m *= (1.0f / 64.0f);
    float dv = xv - m;
    float var = dv * dv;
    #pragma unroll
    for (int o = 32; o; o >>= 1) var += __shfl_xor(var, o, 64);
    var *= (1.0f / 64.0f);
    float xg = dv * (1.0f / sqrtf(var + LNEPS)) * gamma[lane] + beta[lane];
    Xn[row * 64 + lane] = xg;
    xrow[w][lane] = xg;
    __syncthreads();
    float q = bq[lane], k = bk[lane];
    #pragma unroll 8
    for (int e = 0; e < 64; e++) {
        float xe = xrow[w][e];
        q += xe * Wq[e * 64 + lane];
        k += xe * Wk[e * 64 + lane];
    }
    int br = (int)(row / LL);
    int jl = (int)(row - (size_t)br * LL);
    Qb[((size_t)br * LLP + jl) * 64 + lane] = q;
    Kbf[((size_t)br * LLP + jl) * 64 + lane] = f2bf(k);
}

// ---------------- Kernel 1b: transpose Xn -> bf16 X^T, zero all pads ----------------
__global__ __launch_bounds__(256) void k_prep(
    const float* __restrict__ Xn, short* __restrict__ XbfT,
    short* __restrict__ Kbf, float* __restrict__ Qb)
{
    __shared__ float tile[64][65];
    int bb = blockIdx.x & 7;
    int jt = blockIdx.x >> 3;          // 0..38
    int j0 = jt * 64;
    for (int i = threadIdx.x; i < 4096; i += 256) {
        int jl = i >> 6, d = i & 63;
        int j = j0 + jl;
        tile[jl][d] = (j < LL) ? Xn[((size_t)bb * LL + j) * 64 + d] : 0.f;
    }
    __syncthreads();
    for (int i = threadIdx.x; i < 4096; i += 256) {
        int d = i >> 6, jl = i & 63;
        XbfT[((size_t)bb * 64 + d) * LLP + j0 + jl] = f2bf(tile[jl][d]);
    }
    if (jt == 38) {
        for (int i = threadIdx.x; i < (LLP - LL) * 64; i += 256) {
            int jl = i >> 6, d = i & 63;
            Kbf[((size_t)bb * LLP + LL + jl) * 64 + d] = 0;
            Qb [((size_t)bb * LLP + LL + jl) * 64 + d] = 0.f;
        }
    }
}

// ---------------- Kernel 2: fused attn, 512 thr, G in LDS, double-buffered pipeline ----------------
__global__ __launch_bounds__(512, 2) void k_attn(
    const float* __restrict__ Xn, const float* __restrict__ Qb,
    const short* __restrict__ Kbf, const short* __restrict__ XbfT,
    const float* __restrict__ stg, const int* __restrict__ topk_p,
    float* __restrict__ Z)
{
    __shared__ __align__(16) unsigned short Gt[RT * GCOL];   // 133,120 B
    __shared__ __align__(16) unsigned hist[RT * 256];        // 26,624 B (512-bin packed u16x2)
    __shared__ int gmax_lds[RT];
    __shared__ unsigned thr_lds[RT];
    float* redf = (float*)hist;            // union: red[RT*65] + rowsum[RT], hist dead after scan
    float* rowsum = redf + RT * 65;

    int tid = threadIdx.x;
    int lane = tid & 63, wv = tid >> 6;    // wv in [0,8)
    int hi = lane >> 5, l31 = lane & 31;
    int b = blockIdx.x & 7;
    int tile = blockIdx.x >> 3;            // 0..95
    int row0 = tile * RT;

    // ---- init: Gt = sentinel, hist = 0, gmax = 0 ----
    for (int i = tid; i < RT * GCOL / 2; i += 512) ((unsigned*)Gt)[i] = 0xFFFFFFFFu;
    for (int i = tid; i < RT * 256; i += 512) hist[i] = 0u;
    if (tid < RT) gmax_lds[tid] = 0;

    int keff;
    { int tk = *topk_p; keff = (tk < 5) ? tk * NN : tk; }

    // Q A-fragments: row = row0 + l31 (rows >= RT give garbage -> discarded downstream)
    bf16x8 qf[4];
    {
        const float* qp = Qb + ((size_t)b * LLP + row0 + l31) * 64 + hi * 8;
        #pragma unroll
        for (int kk = 0; kk < 4; kk++) {
            bf16x8 f;
            #pragma unroll
            for (int e = 0; e < 8; e++) f[e] = f2bf(qp[kk * 16 + e]);
            qf[kk] = f;
        }
    }
    const float* stgb = stg + (size_t)b * LL * LL;
    int kt0 = wv * TPW;
    int kt1 = (kt0 + TPW < TILES) ? kt0 + TPW : TILES;
    __syncthreads();   // init visible

    // ---- Phase A (double-buffered): coalesced stg + MFMA -> u16 g in LDS + hist + gmax ----
    int gmx[16];
    #pragma unroll
    for (int i = 0; i < 16; i++) gmx[i] = 0;

    float svsA[16]; bf16x8 kvA[4];
    if (kt0 < kt1) {
        int j = kt0 * 32 + l31;
        #pragma unroll
        for (int reg = 0; reg < 16; reg++) {
            int trow = (reg & 3) + 8 * (reg >> 2) + 4 * hi;
            int grow = row0 + trow;
            bool v = (j < LL) && (trow < RT) && (grow < LL);
            svsA[reg] = v ? stgb[(size_t)grow * LL + j] : 0.f;
        }
        const short* kbase = Kbf + ((size_t)b * LLP + j) * 64 + hi * 8;
        kvA[0] = *(const bf16x8*)(kbase);
        kvA[1] = *(const bf16x8*)(kbase + 16);
        kvA[2] = *(const bf16x8*)(kbase + 32);
        kvA[3] = *(const bf16x8*)(kbase + 48);
    }
    for (int kt = kt0; kt < kt1; ++kt) {
        float svsB[16]; bf16x8 kvB[4];
        if (kt + 1 < kt1) {
            int jn = (kt + 1) * 32 + l31;
            #pragma unroll
            for (int reg = 0; reg < 16; reg++) {
                int trow = (reg & 3) + 8 * (reg >> 2) + 4 * hi;
                int grow = row0 + trow;
                bool v = (jn < LL) && (trow < RT) && (grow < LL);
                svsB[reg] = v ? stgb[(size_t)grow * LL + jn] : 0.f;
            }
            const short* kbase = Kbf + ((size_t)b * LLP + jn) * 64 + hi * 8;
            kvB[0] = *(const bf16x8*)(kbase);
            kvB[1] = *(const bf16x8*)(kbase + 16);
            kvB[2] = *(const bf16x8*)(kbase + 32);
            kvB[3] = *(const bf16x8*)(kbase + 48);
        }
        int j = kt * 32 + l31;
        bool vj = (j < LL);
        f32x16 c = {0.f,0.f,0.f,0.f,0.f,0.f,0.f,0.f,0.f,0.f,0.f,0.f,0.f,0.f,0.f,0.f};
        c = __builtin_amdgcn_mfma_f32_32x32x16_bf16(qf[0], kvA[0], c, 0, 0, 0);
        c = __builtin_amdgcn_mfma_f32_32x32x16_bf16(qf[1], kvA[1], c, 0, 0, 0);
        c = __builtin_amdgcn_mfma_f32_32x32x16_bf16(qf[2], kvA[2], c, 0, 0, 0);
        c = __builtin_amdgcn_mfma_f32_32x32x16_bf16(qf[3], kvA[3], c, 0, 0, 0);
        #pragma unroll
        for (int reg = 0; reg < 16; reg++) {
            int trow = (reg & 3) + 8 * (reg >> 2) + 4 * hi;
            int grow = row0 + trow;
            bool v = vj && (trow < RT) && (grow < LL);
            float sg = 1.0f / (1.0f + __expf(c[reg] * -0.125f));
            float s = sg * svsA[reg];
            int g = (int)(s * 65536.0f); g = (g > 65534) ? 65534 : g;
            if (v) {
                unsigned col = (unsigned)j ^ ((unsigned)(trow & 15) << 3);
                Gt[trow * GCOL + col] = (unsigned short)g;
                atomicAdd(&hist[trow * 256 + (g >> 8)], 1u << (((g >> 7) & 1) << 4));
                gmx[reg] = (g > gmx[reg]) ? g : gmx[reg];
            }
        }
        #pragma unroll
        for (int i = 0; i < 16; i++) svsA[i] = svsB[i];
        #pragma unroll
        for (int i = 0; i < 4; i++) kvA[i] = kvB[i];
    }
    #pragma unroll
    for (int reg = 0; reg < 16; reg++) {
        int v = gmx[reg];
        #pragma unroll
        for (int off = 1; off < 32; off <<= 1) {
            int o2 = __shfl_xor(v, off, 64);
            v = (o2 > v) ? o2 : v;
        }
        if (l31 == 0) {
            int trow = (reg & 3) + 8 * (reg >> 2) + 4 * hi;
            if (trow < RT) atomicMax(&gmax_lds[trow], v);
        }
    }
    __syncthreads();   // Gt + hist + gmax complete

    // ---- Phase B: 512-bin scan per row -> threshold (keep g >= thrge) ----
    #pragma unroll 1
    for (int row = wv; row < RT; row += 8) {
        const unsigned* h = &hist[row * 256];
        unsigned w0 = h[lane * 4 + 0], w1 = h[lane * 4 + 1];
        unsigned w2 = h[lane * 4 + 2], w3 = h[lane * 4 + 3];
        unsigned cb[8] = {w0 & 0xFFFFu, w0 >> 16, w1 & 0xFFFFu, w1 >> 16,
                          w2 & 0xFFFFu, w2 >> 16, w3 & 0xFFFFu, w3 >> 16};
        unsigned S = cb[0] + cb[1] + cb[2] + cb[3] + cb[4] + cb[5] + cb[6] + cb[7];
        unsigned T = S;
        #pragma unroll
        for (int off = 1; off < 64; off <<= 1) {
            unsigned t = __shfl_down(T, off, 64);
            T += (lane + off < 64) ? t : 0u;
        }
        unsigned Tn = T - S;
        unsigned sfx[9];
        sfx[8] = Tn;
        #pragma unroll
        for (int i = 7; i >= 0; i--) sfx[i] = cb[i] + sfx[i + 1];
        unsigned kr = (unsigned)keff;
        int hit = -1; unsigned nk = 0, mm = 0;
        #pragma unroll
        for (int i = 0; i < 8; i++) {
            if (sfx[i] >= kr && sfx[i + 1] < kr) { hit = i; nk = kr - sfx[i + 1]; mm = cb[i]; }
        }
        unsigned long long mask = __ballot(hit >= 0);
        if (mask == 0ull) {
            if (lane == 0) thr_lds[row] = 65535u;
        } else {
            int src = __ffsll(mask) - 1;
            int bini = __shfl(hit, src, 64);
            nk = (unsigned)__shfl((int)nk, src, 64);
            mm = (unsigned)__shfl((int)mm, src, 64);
            if (lane == 0) {
                int bin = src * 8 + bini;
                int drop = (2u * nk <= mm) ? 1 : 0;
                int thrge = bin * 128 + (drop ? 128 : 0);
                if (thrge > 65535) thrge = 65535;
                thr_lds[row] = (unsigned)thrge;
            }
        }
    }
    __syncthreads();   // scans done reading hist

    // ---- re-purpose hist region as PV accumulators ----
    for (int i = tid; i < RT * 65 + RT; i += 512) redf[i] = 0.f;
    __syncthreads();

    // ---- Phase C (double-buffered): PV from LDS G-tile ----
    bool av = (l31 < RT);
    int arow = av ? l31 : 0;
    int agmax = av ? gmax_lds[arow] : -1;
    unsigned athr = av ? thr_lds[arow] : 65535u;
    unsigned swz = ((unsigned)(arow & 15)) << 3;
    const unsigned short* gp = &Gt[arow * GCOL];
    const short* xb0 = XbfT + ((size_t)b * 64 + l31) * LLP + hi * 8;
    const short* xb1 = XbfT + ((size_t)b * 64 + 32 + l31) * LLP + hi * 8;
    f32x16 p0 = {0.f,0.f,0.f,0.f,0.f,0.f,0.f,0.f,0.f,0.f,0.f,0.f,0.f,0.f,0.f,0.f};
    f32x16 p1 = p0;
    float smr = 0.f;

    bf16x8 xA[4];
    if (kt0 < kt1) {
        int j0 = kt0 * 32;
        xA[0] = *(const bf16x8*)(xb0 + j0);
        xA[1] = *(const bf16x8*)(xb0 + j0 + 16);
        xA[2] = *(const bf16x8*)(xb1 + j0);
        xA[3] = *(const bf16x8*)(xb1 + j0 + 16);
    }
    for (int kt = kt0; kt < kt1; ++kt) {
        bf16x8 xB[4];
        if (kt + 1 < kt1) {
            int jn = (kt + 1) * 32;
            xB[0] = *(const bf16x8*)(xb0 + jn);
            xB[1] = *(const bf16x8*)(xb0 + jn + 16);
            xB[2] = *(const bf16x8*)(xb1 + jn);
            xB[3] = *(const bf16x8*)(xb1 + jn + 16);
        }
        int j0 = kt * 32;
        bf16x8 ea[2];
        #pragma unroll
        for (int kk = 0; kk < 2; kk++) {
            unsigned colb = (unsigned)(j0 + kk * 16 + hi * 8) ^ swz;
            u16x8 gv = *(const u16x8*)&gp[colb];
            bf16x8 f;
            #pragma unroll
            for (int e = 0; e < 8; e++) {
                unsigned g = gv[e];
                bool keep = (g != SENT) && (g >= athr || (int)g == agmax);
                float ev = keep ? __expf((float)((int)g - agmax) * (1.0f / 65536.0f)) : 0.f;
                smr += ev;
                f[e] = f2bf(ev);
            }
            ea[kk] = f;
        }
        p0 = __builtin_amdgcn_mfma_f32_32x32x16_bf16(ea[0], xA[0], p0, 0, 0, 0);
        p0 = __builtin_amdgcn_mfma_f32_32x32x16_bf16(ea[1], xA[1], p0, 0, 0, 0);
        p1 = __builtin_amdgcn_mfma_f32_32x32x16_bf16(ea[0], xA[2], p1, 0, 0, 0);
        p1 = __builtin_amdgcn_mfma_f32_32x32x16_bf16(ea[1], xA[3], p1, 0, 0, 0);
        #pragma unroll
        for (int i = 0; i < 4; i++) xA[i] = xB[i];
    }
    smr += __shfl_xor(smr, 32, 64);
    if (lane < 32 && l31 < RT) atomicAdd(&rowsum[l31], smr);
    #pragma unroll
    for (int reg = 0; reg < 16; reg++) {
        int trow = (reg & 3) + 8 * (reg >> 2) + 4 * hi;
        if (trow < RT) {
            atomicAdd(&redf[trow * 65 + l31],      p0[reg]);
            atomicAdd(&redf[trow * 65 + 32 + l31], p1[reg]);
        }
    }
    __syncthreads();

    // ---- epilogue: normalize + residual ----
    for (int i = tid; i < RT * 64; i += 512) {
        int r = i >> 6, d = i & 63;
        int grow = row0 + r;
        if (grow < LL) {
            size_t gi = ((size_t)b * LL + grow) * 64 + d;
            Z[gi] = redf[r * 65 + d] * (1.0f / rowsum[r]) + Xn[gi];
        }
    }
}

// ---------------- Kernel 3: fused LN + FFN + residual ----------------
__global__ __launch_bounds__(256) void k_ffn(
    const float* __restrict__ Zb, const float* __restrict__ fg, const float* __restrict__ fb,
    const float* __restrict__ w1, const float* __restrict__ b1,
    const float* __restrict__ w2, const float* __restrict__ b2,
    float* __restrict__ out)
{
    const int G2 = 16;
    __shared__ float zr[G2][64];
    __shared__ float zl[G2][64];
    __shared__ float h[G2][DHID];
    int tid = threadIdx.x;
    int w = tid >> 6, lane = tid & 63;
    size_t row0 = (size_t)blockIdx.x * G2;
    for (int rr = w; rr < G2; rr += 4) {
        float zv = Zb[(row0 + rr) * 64 + lane];
        zr[rr][lane] = zv;
        float m = zv;
        #pragma unroll
        for (int o = 32; o; o >>= 1) m += __shfl_xor(m, o, 64);
        m *= (1.0f / 64.0f);
        float dv = zv - m;
        float var = dv * dv;
        #pragma unroll
        for (int o = 32; o; o >>= 1) var += __shfl_xor(var, o, 64);
        var *= (1.0f / 64.0f);
        zl[rr][lane] = dv * (1.0f / sqrtf(var + LNEPS)) * fg[lane] + fb[lane];
    }
    __syncthreads();
    float hacc[G2];
    #pragma unroll
    for (int g = 0; g < G2; g++) hacc[g] = 0.f;
    for (int d = 0; d < 64; d++) {
        float wv1 = w1[d * DHID + tid];
        #pragma unroll
        for (int g = 0; g < G2; g++) hacc[g] += zl[g][d] * wv1;
    }
    float b1v = b1[tid];
    #pragma unroll
    for (int g = 0; g < G2; g++) h[g][tid] = fmaxf(hacc[g] + b1v, 0.f);
    __syncthreads();
    float oacc[4] = {0.f, 0.f, 0.f, 0.f};
    for (int i = 0; i < DHID; i++) {
        float wv2 = w2[i * 64 + lane];
        #pragma unroll
        for (int rr = 0; rr < 4; rr++) oacc[rr] += h[w * 4 + rr][i] * wv2;
    }
    float b2v = b2[lane];
    #pragma unroll
    for (int rr = 0; rr < 4; rr++)
        out[(row0 + w * 4 + rr) * 64 + lane] = zr[w * 4 + rr][lane] + oacc[rr] + b2v;
}

extern "C" void kernel_launch(void* const* d_in, const int* in_sizes, int n_in,
                              void* d_out, int out_size, void* d_ws, size_t ws_size,
                              hipStream_t stream)
{
    const float* x      = (const float*)d_in[0];
    const float* stg    = (const float*)d_in[1];
    const float* Wq     = (const float*)d_in[2];
    const float* bq     = (const float*)d_in[3];
    const float* Wk     = (const float*)d_in[4];
    const float* bk     = (const float*)d_in[5];
    const float* gamma  = (const float*)d_in[6];
    const float* beta   = (const float*)d_in[7];
    const float* fgamma = (const float*)d_in[8];
    const float* fbeta  = (const float*)d_in[9];
    const float* w1     = (const float*)d_in[10];
    const float* b1     = (const float*)d_in[11];
    const float* w2     = (const float*)d_in[12];
    const float* b2     = (const float*)d_in[13];
    const int*   topk   = (const int*)d_in[14];
    float* out = (float*)d_out;

    const size_t rows  = (size_t)NBATCH * LL;    // 19872
    const size_t prows = (size_t)NBATCH * LLP;   // 19968
    float* Xn = (float*)d_ws;                    // rows*64 f32
    float* Qb = Xn + rows * 64;                  // (prows+64)*64 f32 (padded + tile-overrun slack)
    float* Z  = Qb + (prows + 64) * 64;          // rows*64 f32
    short* Kbf  = (short*)(Z + rows * 64);       // prows*64 bf16
    short* XbfT = Kbf + prows * 64;              // prows*64 bf16 (transposed layout)
    // total ~20.4 MB — proven ws budget

    k_lnproj<<<(int)(rows / 4), 256, 0, stream>>>(x, Wq, bq, Wk, bk, gamma, beta, Xn, Qb, Kbf);
    k_prep<<<NBATCH * 39, 256, 0, stream>>>(Xn, XbfT, Kbf, Qb);
    k_attn<<<NBATCH * NBLK, 512, 0, stream>>>(Xn, Qb, Kbf, XbfT, stg, topk, Z);
    k_ffn<<<(int)(rows / 16), 256, 0, stream>>>(Z, fgamma, fbeta, w1, b1, w2, b2, out);
}